// Round 11
// baseline (6272.414 us; speedup 1.0000x reference)
//
#include <hip/hip_runtime.h>

typedef unsigned short u16;
typedef unsigned int u32;
typedef unsigned long long u64;
typedef __attribute__((ext_vector_type(8))) short bf16x8;   // 8 bf16 = 4 VGPRs
typedef __attribute__((ext_vector_type(4))) float f32x4;

namespace {
constexpr int kT = 1024, kI = 64, kH = 512, kO = 24;
constexpr int kBH = 64 * kH;                  // 32768 elems per h buffer (bf16)
constexpr int kNWG = 132;                     // 64 L1 + 64 L2 + 4 OUT
// h1: 4 bufs, h2: 4 bufs (k mod 4), tags k mod 3, buf3 invalid-init
constexpr unsigned kBarOff = 8u * (unsigned)kBH * 2u;   // 524288 B
// control ints: [0..63] flagL1, [64..127] flagL2, [128..131] flagOUT
// flagX[wg] = X's waves have all VALIDATED their tick-flag inputs (reads done)
}

__device__ __forceinline__ u16 f2bf(float f) {   // round-to-nearest-even
  union { float f; u32 u; } c; c.f = f;
  u32 u = c.u + 0x7FFFu + ((c.u >> 16) & 1u);
  return (u16)(u >> 16);
}
__device__ __forceinline__ float sigf(float x) { return 1.0f / (1.0f + __expf(-x)); }
__device__ __forceinline__ float tanhf_(float x) {
  float e = __expf(2.0f * x); return 1.0f - 2.0f / (e + 1.0f);  // safe at +-inf
}
__device__ __forceinline__ bf16x8 cvt8(const float* p) {  // fp32x8 -> bf16x8 (RNE)
  const float4 f0 = *reinterpret_cast<const float4*>(p);
  const float4 f1 = *reinterpret_cast<const float4*>(p + 4);
  bf16x8 r;
  r[0] = (short)f2bf(f0.x); r[1] = (short)f2bf(f0.y);
  r[2] = (short)f2bf(f0.z); r[3] = (short)f2bf(f0.w);
  r[4] = (short)f2bf(f1.x); r[5] = (short)f2bf(f1.y);
  r[6] = (short)f2bf(f1.z); r[7] = (short)f2bf(f1.w);
  return r;
}
// agent-coherent 16B load (compiler emits sc0 sc1 + waitcnt; R5-proven codegen)
__device__ __forceinline__ bf16x8 ld8c(const u16* p) {
  union { bf16x8 v; u64 q[2]; } r;
  r.q[0] = __hip_atomic_load((const u64*)p,     __ATOMIC_RELAXED, __HIP_MEMORY_SCOPE_AGENT);
  r.q[1] = __hip_atomic_load((const u64*)p + 1, __ATOMIC_RELAXED, __HIP_MEMORY_SCOPE_AGENT);
  return r.v;
}
__device__ __forceinline__ f32x4 mfma(bf16x8 a, bf16x8 b, f32x4 c) {
  return __builtin_amdgcn_mfma_f32_16x16x32_bf16(a, b, c, 0, 0, 0);
}
__device__ __forceinline__ int ldflag(const int* s, int i) {
  return __hip_atomic_load(&s[i], __ATOMIC_RELAXED, __HIP_MEMORY_SCOPE_AGENT);
}
__device__ __forceinline__ void stflag(int* s, int i, int v) {
  __hip_atomic_store(&s[i], v, __ATOMIC_RELAXED, __HIP_MEMORY_SCOPE_AGENT);
}
// tick tag (k mod 3) in LSBs of bf16 elems 0,1 of each 8B granule.
// pat3 emits (0,0),(1,0),(0,1); (1,1) is INVALID = init of buf 3 (R8-proven).
__device__ __forceinline__ u32 pat3(int t3) {
  return ((u32)t3 & 1u) | ((((u32)t3 >> 1) & 1u) << 16);
}
template<int N>
__device__ __forceinline__ bool tagsok(const bf16x8* ch, u32 pat) {
  bool ok = true;
#pragma unroll
  for (int c = 0; c < N; ++c) {
    union { bf16x8 v; u32 u[4]; } t; t.v = ch[c];
    ok = ok && ((t.u[0] & 0x10001u) == pat) && ((t.u[2] & 0x10001u) == pat);
  }
  return ok;
}
// Sentinel poll: spin on chunk 0 only (16B/lane, no sleep -> min detect
// latency), then bulk-load chunks 1..N-1 tag-validated (producer stores all
// granules ~simultaneously; relaxed stores may straggle -> rare micro-retry).
// detect IS the first RT of the data; chain = store-transit + detect + bulk.
template<int N>
__device__ __forceinline__ void pollsent(const u16* p, u32 pat, bf16x8* ch) {
  for (;;) {
    ch[0] = ld8c(p);
    if (__all(tagsok<1>(ch, pat))) break;
  }
  if (N > 1) {
    for (;;) {
#pragma unroll
      for (int c = 1; c < N; ++c) ch[c] = ld8c(p + c * 32);
      if (__all(tagsok<N - 1>(ch + 1, pat))) break;
    }
  }
  __asm__ volatile("" ::: "memory");
}
// tagged h store: 4 bf16 + 2 tag bits, ONE agent-scope atomic 8B store.
// Issued with NO drain on the critical path -- transits while producer loops.
__device__ __forceinline__ void st_h(u16* p, const float* h, int t3) {
  u16 a = (u16)((f2bf(h[0]) & ~1u) | ((u32)t3 & 1u));
  u16 b = (u16)((f2bf(h[1]) & ~1u) | (((u32)t3 >> 1) & 1u));
  u64 v = (u64)a | ((u64)b << 16) | ((u64)f2bf(h[2]) << 32) | ((u64)f2bf(h[3]) << 48);
  __hip_atomic_store((u64*)p, v, __ATOMIC_RELAXED, __HIP_MEMORY_SCOPE_AGENT);
}
// Anti-overwrite throttles (run on a NON-update wave, pre-barrier, cached ->
// nearly always free). Overwriting h[j] at tick j+4 requires: own-layer peers
// have validated tick j+1 inputs (flag >= j+1) and downstream (L2/OUT) have
// validated tick j (flag >= j). With j = k-4 at tick k: peers >= k-3,
// downstream >= k-4. Without this, a lagging consumer spins forever on an
// overwritten tag (deadlock) -- flags are required, but only here, off-path.
__device__ __forceinline__ void throttleL1(const int* ctl, int g, int k, int& bound) {
  if (bound >= k) return;
  const int lane = threadIdx.x & 63;
  for (;;) {
    int a = (lane < 32) ? ldflag(ctl, g * 32 + lane) : 0x7fffffff;            // L1 peers
    int b = (lane < 32) ? ldflag(ctl, 64 + g * 32 + lane) + 1 : 0x7fffffff;   // L2 (+1: slack 4)
    int c2 = (lane < 2) ? ldflag(ctl, 128 + g * 2 + lane) + 1 : 0x7fffffff;   // OUT
    int m = min(min(a, b), c2);
    if (__all(m >= k - 3)) { bound = __all(m >= k) ? k + 3 : k; break; }
    __builtin_amdgcn_s_sleep(1);
  }
}
__device__ __forceinline__ void throttleL2(const int* ctl, int g, int k, int& bound) {
  if (bound >= k) return;
  const int lane = threadIdx.x & 63;
  for (;;) {
    int a = (lane < 32) ? ldflag(ctl, 64 + g * 32 + lane) : 0x7fffffff;       // L2 peers
    int c2 = (lane < 2) ? ldflag(ctl, 128 + g * 2 + lane) + 1 : 0x7fffffff;   // OUT
    int m = min(a, c2);
    if (__all(m >= k - 3)) { bound = __all(m >= k) ? k + 3 : k; break; }
    __builtin_amdgcn_s_sleep(1);
  }
}

// Roles (132 WGs x 512 threads, free-running, tag dataflow, ONE barrier/tick):
//   wg   0..63 : layer-1 GRU. u0=(wg&31)*16 units, b0=(wg>>5)*32 batch.
//                waves (ntl=w&1, kh=w>>1: 4 K-quarters). tick k -> h1[k]
//   wg  64..127: layer-2 GRU. waves (ntl, mat, kh: 2 K-halves). -> h2[k]
//   wg 128..131: output head, 16 batch each. tick k -> out[k-1]
// LDS partials are PARITY-alternated (red[k&1]) -> single barrier per tick:
// barrier(k+1) separates kh0's red[k&1] reads from tick-(k+2) writes.
// MFMA 16x16x32 frags: A m=l15,k=q*8+j ; B n=l15,k=q*8+j ; C/D col=l15,row=q*4+r
__global__ __launch_bounds__(512, 1) void stackgru(
    const float* __restrict__ x,
    const float* __restrict__ wih1, const float* __restrict__ whh1,
    const float* __restrict__ bih1, const float* __restrict__ bhh1,
    const float* __restrict__ wih2, const float* __restrict__ whh2,
    const float* __restrict__ bih2, const float* __restrict__ bhh2,
    const float* __restrict__ wo1, const float* __restrict__ bo1,
    const float* __restrict__ wo2, const float* __restrict__ bo2,
    float* __restrict__ out, u16* __restrict__ hbuf, int* __restrict__ ctl)
{
  __shared__ float red[2][2][3][3][64][4];   // [par][ntl|rt][src][gate][lane][r] 36 KB
  const int wg = blockIdx.x;
  const int tid = threadIdx.x;
  const int lane = tid & 63;
  const int w = tid >> 6;
  const int l15 = lane & 15;
  const int q = lane >> 4;

  int* flagL1  = ctl;
  int* flagL2  = ctl + 64;
  int* flagOUT = ctl + 128;
  u16* h1b = hbuf;                     // 4 * kBH
  u16* h2b = hbuf + 4 * kBH;           // 4 * kBH

  if (wg < 64) {
    // ---------------- layer 1 ----------------
    const int u0 = (wg & 31) * 16, g = wg >> 5, b0 = g * 32;
    const int ntl = w & 1, kh = w >> 1;        // kh = K-quarter (0..3)
    const int bb = b0 + ntl * 16 + l15;
    bf16x8 ahh[3][4];                           // 48 VGPRs w_hh1 frags
#pragma unroll
    for (int gg = 0; gg < 3; ++gg)
#pragma unroll
      for (int c = 0; c < 4; ++c)
        ahh[gg][c] = cvt8(whh1 + (gg * kH + u0 + l15) * kH + (kh * 4 + c) * 32 + q * 8);
    bf16x8 aih[3][2];
    float br[4], bz[4], bni[4], bnh[4], h1l[4];
    int bound = 0;
    if (kh == 0) {
#pragma unroll
      for (int gg = 0; gg < 3; ++gg)
#pragma unroll
        for (int c = 0; c < 2; ++c)
          aih[gg][c] = cvt8(wih1 + (gg * kH + u0 + l15) * kI + c * 32 + q * 8);
#pragma unroll
      for (int r = 0; r < 4; ++r) {
        int u = u0 + q * 4 + r;
        br[r]  = bih1[u]          + bhh1[u];
        bz[r]  = bih1[kH + u]     + bhh1[kH + u];
        bni[r] = bih1[2 * kH + u];
        bnh[r] = bhh1[2 * kH + u];
        h1l[r] = 0.0f;                  // fp32 master h1 lives in regs
      }
    }
    for (int k = 1; k <= kT; ++k) {
      const int par = k & 1;
      const int t3 = k % 3, t3p = (k - 1) % 3;
      bf16x8 xf0, xf1;
      if (kh == 0) {                    // x prefetch (plain cached loads)
        const float* xs = x + (bb * kT + (k - 1)) * kI + q * 8;
        xf0 = cvt8(xs); xf1 = cvt8(xs + 32);
      }
      if (w == 7) throttleL1(ctl, g, k, bound);   // off update path
      bf16x8 ch[4];
      pollsent<4>(h1b + ((k - 1) & 3) * kBH + bb * kH + kh * 128 + q * 8, pat3(t3p), ch);
      f32x4 a0 = {0,0,0,0}, a1 = {0,0,0,0}, a2 = {0,0,0,0};
#pragma unroll
      for (int c = 0; c < 4; ++c) {
        a0 = mfma(ahh[0][c], ch[c], a0);
        a1 = mfma(ahh[1][c], ch[c], a1);
        a2 = mfma(ahh[2][c], ch[c], a2);
      }
      f32x4 x0 = {0,0,0,0}, x1 = {0,0,0,0}, x2 = {0,0,0,0};
      if (kh != 0) {
#pragma unroll
        for (int r = 0; r < 4; ++r) {
          red[par][ntl][kh - 1][0][lane][r] = a0[r];
          red[par][ntl][kh - 1][1][lane][r] = a1[r];
          red[par][ntl][kh - 1][2][lane][r] = a2[r];
        }
      } else {
        x0 = mfma(aih[0][0], xf0, x0); x0 = mfma(aih[0][1], xf1, x0);
        x1 = mfma(aih[1][0], xf0, x1); x1 = mfma(aih[1][1], xf1, x1);
        x2 = mfma(aih[2][0], xf0, x2); x2 = mfma(aih[2][1], xf1, x2);
      }
      __syncthreads();                  // the ONE barrier of tick k
      if (tid == 448) stflag(flagL1, wg, k);   // all waves validated h1[k-1]
      if (kh == 0) {
        float hnew[4];
#pragma unroll
        for (int r = 0; r < 4; ++r) {
          float gh0 = a0[r] + red[par][ntl][0][0][lane][r] + red[par][ntl][1][0][lane][r] + red[par][ntl][2][0][lane][r];
          float gh1 = a1[r] + red[par][ntl][0][1][lane][r] + red[par][ntl][1][1][lane][r] + red[par][ntl][2][1][lane][r];
          float gh2 = a2[r] + red[par][ntl][0][2][lane][r] + red[par][ntl][1][2][lane][r] + red[par][ntl][2][2][lane][r];
          float rr = sigf(x0[r] + gh0 + br[r]);
          float zz = sigf(x1[r] + gh1 + bz[r]);
          float nn = tanhf_(x2[r] + bni[r] + rr * (gh2 + bnh[r]));
          float h  = (1.0f - zz) * nn + zz * h1l[r];
          h1l[r] = h; hnew[r] = h;
        }
        st_h(h1b + (k & 3) * kBH + bb * kH + u0 + q * 4, hnew, t3);  // no drain
      }
    }
  } else if (wg < 128) {
    // ---------------- layer 2 ----------------
    const int g2 = wg - 64;
    const int u0 = (g2 & 31) * 16, g = g2 >> 5, b0 = g * 32;
    const int ntl = w & 1, mat = (w >> 1) & 1, kh = w >> 2;  // kh = K-half
    const int bb = b0 + ntl * 16 + l15;
    const float* wsrc = mat ? whh2 : wih2;
    bf16x8 af[3][8];                            // 96 VGPRs resident weights
#pragma unroll
    for (int gg = 0; gg < 3; ++gg)
#pragma unroll
      for (int c = 0; c < 8; ++c)
        af[gg][c] = cvt8(wsrc + (gg * kH + u0 + l15) * kH + (kh * 8 + c) * 32 + q * 8);
    const bool upd = (mat == 0 && kh == 0);
    float br[4], bz[4], bni[4], bnh[4], h2l[4];
    int bound = 0;
    if (upd) {
#pragma unroll
      for (int r = 0; r < 4; ++r) {
        int u = u0 + q * 4 + r;
        br[r]  = bih2[u]          + bhh2[u];
        bz[r]  = bih2[kH + u]     + bhh2[kH + u];
        bni[r] = bih2[2 * kH + u];
        bnh[r] = bhh2[2 * kH + u];
        h2l[r] = 0.0f;
      }
    }
    for (int k = 1; k <= kT; ++k) {
      const int par = k & 1;
      const int t3 = k % 3, t3p = (k - 1) % 3;
      if (w == 7) throttleL2(ctl, g, k, bound);
      const u16* base = (mat == 0) ? h1b + (k & 3) * kBH : h2b + ((k - 1) & 3) * kBH;
      bf16x8 ch[8];
      pollsent<8>(base + bb * kH + kh * 256 + q * 8, pat3(mat == 0 ? t3 : t3p), ch);
      f32x4 a0 = {0,0,0,0}, a1 = {0,0,0,0}, a2 = {0,0,0,0};
#pragma unroll
      for (int c = 0; c < 8; ++c) {
        a0 = mfma(af[0][c], ch[c], a0);
        a1 = mfma(af[1][c], ch[c], a1);
        a2 = mfma(af[2][c], ch[c], a2);
      }
      if (!upd) {
        const int s = mat * 2 + kh - 1;   // (0,1)->0 (1,0)->1 (1,1)->2
#pragma unroll
        for (int r = 0; r < 4; ++r) {
          red[par][ntl][s][0][lane][r] = a0[r];
          red[par][ntl][s][1][lane][r] = a1[r];
          red[par][ntl][s][2][lane][r] = a2[r];
        }
      }
      __syncthreads();                  // the ONE barrier of tick k
      if (tid == 448) stflag(flagL2, g2, k);   // h1[k] & h2[k-1] validated
      if (upd) {
        float hnew[4];
#pragma unroll
        for (int r = 0; r < 4; ++r) {
          float gi0 = a0[r] + red[par][ntl][0][0][lane][r];
          float gi1 = a1[r] + red[par][ntl][0][1][lane][r];
          float gi2 = a2[r] + red[par][ntl][0][2][lane][r];
          float gh0 = red[par][ntl][1][0][lane][r] + red[par][ntl][2][0][lane][r];
          float gh1 = red[par][ntl][1][1][lane][r] + red[par][ntl][2][1][lane][r];
          float gh2 = red[par][ntl][1][2][lane][r] + red[par][ntl][2][2][lane][r];
          float rr = sigf(gi0 + gh0 + br[r]);
          float zz = sigf(gi1 + gh1 + bz[r]);
          float nn = tanhf_(gi2 + bni[r] + rr * (gh2 + bnh[r]));
          float h  = (1.0f - zz) * nn + zz * h2l[r];
          h2l[r] = h; hnew[r] = h;
        }
        st_h(h2b + (k & 3) * kBH + bb * kH + u0 + q * 4, hnew, t3);
      }
    }
  } else {
    // ---------------- output head ----------------
    const int g3 = wg - 128;
    const int bb = g3 * 16 + l15;
    const int mat = w & 1, khh = (w >> 1) & 1, rt = w >> 2;
    const float* wsel = mat ? wo2 : wo1;
    const int row = rt * 16 + l15;
    bf16x8 zf = {0,0,0,0,0,0,0,0};
    bf16x8 af[8];
#pragma unroll
    for (int c = 0; c < 8; ++c)
      af[c] = (row < kO) ? cvt8(wsel + row * kH + (khh * 8 + c) * 32 + q * 8) : zf;
    const bool fin = (mat == 0 && khh == 0);
    float bv1[4], bv2[4];
    if (fin) {
#pragma unroll
      for (int r = 0; r < 4; ++r) {
        int o = rt * 16 + q * 4 + r;
        bv1[r] = (o < kO) ? bo1[o] : 0.0f;
        bv2[r] = (o < kO) ? bo2[o] : 0.0f;
      }
    }
    const u16* hb = (mat == 0) ? h1b : h2b;
    for (int k = 1; k <= kT; ++k) {
      const int par = k & 1;
      const u32 pat = pat3(k % 3);
      bf16x8 ch[8];
      pollsent<8>(hb + (k & 3) * kBH + bb * kH + khh * 256 + q * 8, pat, ch);
      f32x4 a0 = {0,0,0,0};
#pragma unroll
      for (int c = 0; c < 8; ++c) a0 = mfma(af[c], ch[c], a0);
      if (!fin) {
        const int s = mat * 2 + khh - 1;
#pragma unroll
        for (int r = 0; r < 4; ++r) red[par][rt][s][0][lane][r] = a0[r];
      }
      __syncthreads();                  // the ONE barrier of tick k
      if (tid == 448) stflag(flagOUT, g3, k);
      if (fin) {
        int o0 = rt * 16 + q * 4;
        if (o0 < kO) {
          float4 ov;
          ov.x = tanhf_(a0[0] + red[par][rt][0][0][lane][0] + bv1[0]) +
                 tanhf_(red[par][rt][1][0][lane][0] + red[par][rt][2][0][lane][0] + bv2[0]);
          ov.y = tanhf_(a0[1] + red[par][rt][0][0][lane][1] + bv1[1]) +
                 tanhf_(red[par][rt][1][0][lane][1] + red[par][rt][2][0][lane][1] + bv2[1]);
          ov.z = tanhf_(a0[2] + red[par][rt][0][0][lane][2] + bv1[2]) +
                 tanhf_(red[par][rt][1][0][lane][2] + red[par][rt][2][0][lane][2] + bv2[2]);
          ov.w = tanhf_(a0[3] + red[par][rt][0][0][lane][3] + bv1[3]) +
                 tanhf_(red[par][rt][1][0][lane][3] + red[par][rt][2][0][lane][3] + bv2[3]);
          *reinterpret_cast<float4*>(out + (bb * kT + (k - 1)) * kO + o0) = ov;
        }
      }
    }
  }
}

extern "C" void kernel_launch(void* const* d_in, const int* in_sizes, int n_in,
                              void* d_out, int out_size, void* d_ws, size_t ws_size,
                              hipStream_t stream) {
  (void)in_sizes; (void)n_in; (void)out_size; (void)ws_size;
  // zero h buffers + control page; invalid-tag init for buf 3 of h1 & h2
  hipMemsetAsync(d_ws, 0, kBarOff + 1024, stream);
  hipMemsetAsync((char*)d_ws + 3u * kBH * 2u, 0x01, kBH * 2u, stream);  // h1 buf3
  hipMemsetAsync((char*)d_ws + 7u * kBH * 2u, 0x01, kBH * 2u, stream);  // h2 buf3
  const float* x    = (const float*)d_in[0];
  const float* wih1 = (const float*)d_in[1];
  const float* whh1 = (const float*)d_in[2];
  const float* bih1 = (const float*)d_in[3];
  const float* bhh1 = (const float*)d_in[4];
  const float* wih2 = (const float*)d_in[5];
  const float* whh2 = (const float*)d_in[6];
  const float* bih2 = (const float*)d_in[7];
  const float* bhh2 = (const float*)d_in[8];
  const float* wo1  = (const float*)d_in[9];
  const float* bo1  = (const float*)d_in[10];
  const float* wo2  = (const float*)d_in[11];
  const float* bo2  = (const float*)d_in[12];
  float* out  = (float*)d_out;
  u16* hbuf   = (u16*)d_ws;
  int* ctl    = (int*)((char*)d_ws + kBarOff);
  stackgru<<<dim3(kNWG), dim3(512), 0, stream>>>(
      x, wih1, whh1, bih1, bhh1, wih2, whh2, bih2, bhh2,
      wo1, bo1, wo2, bo2, out, hbuf, ctl);
}